// Round 2
// baseline (194.397 us; speedup 1.0000x reference)
//
#include <hip/hip_runtime.h>

typedef unsigned short u16;
typedef unsigned int u32;
typedef __attribute__((ext_vector_type(8))) short short8;
typedef __attribute__((ext_vector_type(4))) float f32x4;

__device__ __forceinline__ float bl(u32 u){ return __builtin_bit_cast(float, u << 16); }
__device__ __forceinline__ float bh(u32 u){ return __builtin_bit_cast(float, u & 0xffff0000u); }
__device__ __forceinline__ float bf2f(u16 h){ return __builtin_bit_cast(float, ((u32)h) << 16); }
__device__ __forceinline__ u16 f2bf(float f){
  u32 u = __builtin_bit_cast(u32, f);
  u32 r = u + 0x7fffu + ((u >> 16) & 1u);
  return (u16)(r >> 16);
}

// ------- Kernel 0: x fp32 [b][c][hw] -> XTh/XTl bf16 hi/lo split, pixel-major [pix][c] -------
__global__ __launch_bounds__(256) void split_in(const float* __restrict__ x,
                                                u16* __restrict__ XTh,
                                                u16* __restrict__ XTl)
{
  __shared__ float tile[64 * 68];   // [c_local][hw_local], stride 68 (rows 16B-aligned)
  int t = threadIdx.x;
  int hw0 = blockIdx.x * 64, c0 = blockIdx.y * 64, b = blockIdx.z;
  {
    int cl = t >> 2, seg = (t & 3) * 16;
    const float* src = x + (b * 256 + c0 + cl) * 4096 + hw0 + seg;
    float4 v0 = ((const float4*)src)[0];
    float4 v1 = ((const float4*)src)[1];
    float4 v2 = ((const float4*)src)[2];
    float4 v3 = ((const float4*)src)[3];
    float* d = tile + cl * 68 + seg;
    ((float4*)d)[0] = v0; ((float4*)d)[1] = v1;
    ((float4*)d)[2] = v2; ((float4*)d)[3] = v3;
  }
  __syncthreads();
  {
    int hwl = t >> 2, cs = (t & 3) * 16;
    u32 ph[8], pl[8];
    #pragma unroll
    for (int e = 0; e < 8; ++e) {
      float v0 = tile[(cs + 2 * e) * 68 + hwl];
      float v1 = tile[(cs + 2 * e + 1) * 68 + hwl];
      u16 h0 = f2bf(v0), h1 = f2bf(v1);
      u16 l0 = f2bf(v0 - bf2f(h0)), l1 = f2bf(v1 - bf2f(h1));
      ph[e] = (u32)h0 | ((u32)h1 << 16);
      pl[e] = (u32)l0 | ((u32)l1 << 16);
    }
    int off = (b * 4096 + hw0 + hwl) * 256 + c0 + cs;
    *(uint4*)(XTh + off)     = make_uint4(ph[0], ph[1], ph[2], ph[3]);
    *(uint4*)(XTh + off + 8) = make_uint4(ph[4], ph[5], ph[6], ph[7]);
    *(uint4*)(XTl + off)     = make_uint4(pl[0], pl[1], pl[2], pl[3]);
    *(uint4*)(XTl + off + 8) = make_uint4(pl[4], pl[5], pl[6], pl[7]);
  }
}

// ------- Kernel 1: q/k via 3-pass split-bf16 MFMA (fp32-accurate), v via 1-pass bf16 -------
// grid (128, 2, 3). z=0->q (fp32), z=1->k (fp32), z=2->v (bf16).
// Block 256 = 4 waves; tile 128(pix) x 128(o); each wave a 64x64 quadrant.
#define LSTR 40   // padded LDS row stride in bf16 elems (80 B: 16B-aligned, conflict-friendly)
__global__ __launch_bounds__(256) void qkv_gemm(const u16* __restrict__ XTh,
                                                const u16* __restrict__ XTl,
                                                const float* __restrict__ w1,
                                                const float* __restrict__ w2,
                                                const float* __restrict__ w3,
                                                float* __restrict__ qo,
                                                float* __restrict__ ko,
                                                u16* __restrict__ vo)
{
  __shared__ u16 lAh[128 * LSTR];
  __shared__ u16 lBh[128 * LSTR];
  __shared__ u16 lAl[128 * LSTR];
  __shared__ u16 lBl[128 * LSTR];
  int z = blockIdx.z;
  const float* W = (z == 0) ? w1 : ((z == 1) ? w2 : w3);
  int t = threadIdx.x;
  int lane = t & 63, wv = t >> 6;
  int ln15 = lane & 15, q = lane >> 4;
  int pix0 = blockIdx.x * 128;
  int o0 = blockIdx.y * 128;
  int pw = (wv >> 1) * 64, ow = (wv & 1) * 64;
  f32x4 acc[4][4];
  #pragma unroll
  for (int i = 0; i < 4; ++i)
    #pragma unroll
    for (int j = 0; j < 4; ++j)
      acc[i][j] = (f32x4){0.f, 0.f, 0.f, 0.f};

  int srow = t >> 1;
  int sseg = (t & 1) * 16;
  const u16* gAh = XTh + (pix0 + srow) * 256 + sseg;
  const u16* gAl = XTl + (pix0 + srow) * 256 + sseg;
  const float* gB = W + (o0 + srow) * 256 + sseg;
  u16* sAh = lAh + srow * LSTR + sseg;
  u16* sAl = lAl + srow * LSTR + sseg;
  u16* sBh = lBh + srow * LSTR + sseg;
  u16* sBl = lBl + srow * LSTR + sseg;

  for (int kc = 0; kc < 256; kc += 32) {
    uint4 ah0 = *(const uint4*)(gAh + kc);
    uint4 ah1 = *(const uint4*)(gAh + kc + 8);
    uint4 al0 = make_uint4(0, 0, 0, 0), al1 = make_uint4(0, 0, 0, 0);
    if (z < 2) {
      al0 = *(const uint4*)(gAl + kc);
      al1 = *(const uint4*)(gAl + kc + 8);
    }
    float fv[16];
    *(float4*)(fv)      = ((const float4*)(gB + kc))[0];
    *(float4*)(fv + 4)  = ((const float4*)(gB + kc))[1];
    *(float4*)(fv + 8)  = ((const float4*)(gB + kc))[2];
    *(float4*)(fv + 12) = ((const float4*)(gB + kc))[3];
    u32 pbh[8], pbl[8];
    #pragma unroll
    for (int e = 0; e < 8; ++e) {
      float v0 = fv[2 * e], v1 = fv[2 * e + 1];
      u16 h0 = f2bf(v0), h1 = f2bf(v1);
      u16 l0 = f2bf(v0 - bf2f(h0)), l1 = f2bf(v1 - bf2f(h1));
      pbh[e] = (u32)h0 | ((u32)h1 << 16);
      pbl[e] = (u32)l0 | ((u32)l1 << 16);
    }
    __syncthreads();                      // WAR: previous iter's frag reads done
    *(uint4*)sAh = ah0; *(uint4*)(sAh + 8) = ah1;
    *(uint4*)sBh = make_uint4(pbh[0], pbh[1], pbh[2], pbh[3]);
    *(uint4*)(sBh + 8) = make_uint4(pbh[4], pbh[5], pbh[6], pbh[7]);
    if (z < 2) {
      *(uint4*)sAl = al0; *(uint4*)(sAl + 8) = al1;
      *(uint4*)sBl = make_uint4(pbl[0], pbl[1], pbl[2], pbl[3]);
      *(uint4*)(sBl + 8) = make_uint4(pbl[4], pbl[5], pbl[6], pbl[7]);
    }
    __syncthreads();
    short8 afh[4], bfh[4];
    #pragma unroll
    for (int i = 0; i < 4; ++i)
      afh[i] = *(const short8*)(lAh + (pw + i * 16 + ln15) * LSTR + q * 8);
    #pragma unroll
    for (int j = 0; j < 4; ++j)
      bfh[j] = *(const short8*)(lBh + (ow + j * 16 + ln15) * LSTR + q * 8);
    #pragma unroll
    for (int i = 0; i < 4; ++i)
      #pragma unroll
      for (int j = 0; j < 4; ++j)
        acc[i][j] = __builtin_amdgcn_mfma_f32_16x16x32_bf16(afh[i], bfh[j], acc[i][j], 0, 0, 0);
    if (z < 2) {
      short8 afl[4], bfl[4];
      #pragma unroll
      for (int i = 0; i < 4; ++i)
        afl[i] = *(const short8*)(lAl + (pw + i * 16 + ln15) * LSTR + q * 8);
      #pragma unroll
      for (int j = 0; j < 4; ++j)
        bfl[j] = *(const short8*)(lBl + (ow + j * 16 + ln15) * LSTR + q * 8);
      #pragma unroll
      for (int i = 0; i < 4; ++i)
        #pragma unroll
        for (int j = 0; j < 4; ++j) {
          acc[i][j] = __builtin_amdgcn_mfma_f32_16x16x32_bf16(afh[i], bfl[j], acc[i][j], 0, 0, 0);
          acc[i][j] = __builtin_amdgcn_mfma_f32_16x16x32_bf16(afl[i], bfh[j], acc[i][j], 0, 0, 0);
        }
    }
  }

  // D layout: m = pw + i*16 + q*4 + r (pixel), n = ow + j*16 + ln15 (o)
  #pragma unroll
  for (int i = 0; i < 4; ++i) {
    #pragma unroll
    for (int r = 0; r < 4; ++r) {
      int pix = pix0 + pw + i * 16 + q * 4 + r;
      int ob = o0 + ow + ln15;
      if (z == 2) {
        u16* d = vo + pix * 256 + ob;
        #pragma unroll
        for (int j = 0; j < 4; ++j) d[j * 16] = f2bf(acc[i][j][r]);
      } else {
        float* d = ((z == 0) ? qo : ko) + pix * 256 + ob;
        #pragma unroll
        for (int j = 0; j < 4; ++j) d[j * 16] = acc[i][j][r];
      }
    }
  }
}

// ------- Kernel 2: local attention, one wave per pixel. q/k fp32, v bf16, out fp32 -------
// NOTE: outt aliases x1t (q): wave p reads q[p] strictly before writing outt[p]; no
// cross-wave access to q[p]. So no __restrict__ on x1t/outt.
__global__ __launch_bounds__(256) void attn(const float* x1t,
                                            const float* __restrict__ x2t,
                                            const u16* __restrict__ x3t,
                                            float* outt)
{
  __shared__ float lg[4][52];
  __shared__ float wsm[4][52];
  int t = threadIdx.x;
  int wv = t >> 6, lane = t & 63;
  int p = blockIdx.x * 4 + wv;
  int b = p >> 12, hw = p & 4095;
  int h = hw >> 6, w = hw & 63;
  int cg = lane & 15, kk = lane >> 4;
  int pbase = b << 12;

  // q: lane handles channels [cg*16, cg*16+16)
  const float* qp = x1t + p * 256 + cg * 16;
  float4 q0 = *(const float4*)qp;
  float4 q1 = *(const float4*)(qp + 4);
  float4 q2 = *(const float4*)(qp + 8);
  float4 q3 = *(const float4*)(qp + 12);

  // logits: 4 k's at a time (kk = lane>>4), 16 c-groups reduced by 4-step shfl
  for (int kb = 0; kb < 52; kb += 4) {
    int k = kb + kk;
    float partial = 0.f;
    if (k < 49) {
      int dh = k / 7, dw = k % 7;
      int nh = h + dh - 3, nw = w + dw - 3;
      if ((u32)nh < 64u && (u32)nw < 64u) {
        const float* kp = x2t + (pbase + (nh << 6) + nw) * 256 + cg * 16;
        float4 k0 = *(const float4*)kp;
        float4 k1 = *(const float4*)(kp + 4);
        float4 k2 = *(const float4*)(kp + 8);
        float4 k3 = *(const float4*)(kp + 12);
        partial = q0.x * k0.x + q0.y * k0.y + q0.z * k0.z + q0.w * k0.w
                + q1.x * k1.x + q1.y * k1.y + q1.z * k1.z + q1.w * k1.w
                + q2.x * k2.x + q2.y * k2.y + q2.z * k2.z + q2.w * k2.w
                + q3.x * k3.x + q3.y * k3.y + q3.z * k3.z + q3.w * k3.w;
      }
      // OOB neighbor: zero-padded patch -> logit exactly 0 (partial stays 0)
    }
    partial += __shfl_xor(partial, 1);
    partial += __shfl_xor(partial, 2);
    partial += __shfl_xor(partial, 4);
    partial += __shfl_xor(partial, 8);
    if (cg == 0 && k < 49) lg[wv][k] = partial;
  }
  __syncthreads();

  // softmax over 49 (OOB zeros included in denominator — matches zero-padded ref)
  float lv = (lane < 49) ? lg[wv][lane] : -3.0e38f;
  float m = lv;
  #pragma unroll
  for (int msk = 1; msk < 64; msk <<= 1) m = fmaxf(m, __shfl_xor(m, msk));
  float e = (lane < 49) ? __expf(lv - m) : 0.f;
  float s = e;
  #pragma unroll
  for (int msk = 1; msk < 64; msk <<= 1) s += __shfl_xor(s, msk);
  if (lane < 49) wsm[wv][lane] = e / s;
  __syncthreads();

  // weighting: lane handles 4 contiguous channels
  float a0 = 0.f, a1 = 0.f, a2 = 0.f, a3 = 0.f;
  int c0 = lane * 4;
  for (int dh = 0; dh < 7; ++dh) {
    int nh = h + dh - 3;
    if ((u32)nh >= 64u) continue;   // zero value patch -> contributes nothing
    #pragma unroll
    for (int dw = 0; dw < 7; ++dw) {
      int nw = w + dw - 3;
      if ((u32)nw >= 64u) continue;
      float wk = wsm[wv][dh * 7 + dw];
      const u16* vp = x3t + (pbase + (nh << 6) + nw) * 256 + c0;
      uint2 vv = *(const uint2*)vp;
      a0 += wk * bl(vv.x); a1 += wk * bh(vv.x);
      a2 += wk * bl(vv.y); a3 += wk * bh(vv.y);
    }
  }
  *(float4*)(outt + p * 256 + c0) = make_float4(a0, a1, a2, a3);
}

// ------- Kernel 3: outt fp32 [pix][c] -> out fp32 [b][c][hw] -------
__global__ __launch_bounds__(256) void transpose_out(const float* __restrict__ outt,
                                                     float* __restrict__ out)
{
  __shared__ float tile[64 * 68];   // [hw_local][c_local]
  int t = threadIdx.x;
  int hw0 = blockIdx.x * 64, c0 = blockIdx.y * 64, b = blockIdx.z;
  {
    int pl = t >> 2, seg = (t & 3) * 16;
    const float* src = outt + (b * 4096 + hw0 + pl) * 256 + c0 + seg;
    float4 v0 = ((const float4*)src)[0];
    float4 v1 = ((const float4*)src)[1];
    float4 v2 = ((const float4*)src)[2];
    float4 v3 = ((const float4*)src)[3];
    float* d = tile + pl * 68 + seg;
    ((float4*)d)[0] = v0; ((float4*)d)[1] = v1;
    ((float4*)d)[2] = v2; ((float4*)d)[3] = v3;
  }
  __syncthreads();
  {
    int cl = t >> 2, hs = (t & 3) * 16;
    float vv[16];
    #pragma unroll
    for (int e = 0; e < 16; ++e) vv[e] = tile[(hs + e) * 68 + cl];
    float* dst = out + (b * 256 + c0 + cl) * 4096 + hw0 + hs;
    ((float4*)dst)[0] = make_float4(vv[0], vv[1], vv[2], vv[3]);
    ((float4*)dst)[1] = make_float4(vv[4], vv[5], vv[6], vv[7]);
    ((float4*)dst)[2] = make_float4(vv[8], vv[9], vv[10], vv[11]);
    ((float4*)dst)[3] = make_float4(vv[12], vv[13], vv[14], vv[15]);
  }
}

extern "C" void kernel_launch(void* const* d_in, const int* in_sizes, int n_in,
                              void* d_out, int out_size, void* d_ws, size_t ws_size,
                              hipStream_t stream)
{
  const float* x  = (const float*)d_in[0];
  const float* w1 = (const float*)d_in[1];
  const float* w2 = (const float*)d_in[2];
  const float* w3 = (const float*)d_in[3];
  float* out = (float*)d_out;

  // x hi/lo split scratch lives inside d_out (16 MB = 8 MB hi + 8 MB lo);
  // it is consumed by qkv_gemm and then fully overwritten by transpose_out.
  u16* XTh = (u16*)d_out;
  u16* XTl = XTh + 4194304;

  char* ws = (char*)d_ws;
  float* qo = (float*)ws;                 // 16 MB fp32 (query, pixel-major)
  float* ko = (float*)(ws + (16u << 20)); // 16 MB fp32 (key)
  u16*  vo  = (u16*)(ws + (32u << 20));   //  8 MB bf16 (value)
  float* outt = qo;                       // attn output aliases q (safe, see attn)

  split_in<<<dim3(64, 4, 4), 256, 0, stream>>>(x, XTh, XTl);
  qkv_gemm<<<dim3(128, 2, 3), 256, 0, stream>>>(XTh, XTl, w1, w2, w3, qo, ko, vo);
  attn<<<4096, 256, 0, stream>>>(qo, ko, vo, outt);
  transpose_out<<<dim3(64, 4, 4), 256, 0, stream>>>(outt, out);
}